// Round 6
// baseline (206.209 us; speedup 1.0000x reference)
//
#include <hip/hip_runtime.h>
#include <hip/hip_bf16.h>
#include <math.h>

#define VOCAB 100000
#define EMB 100
#define HID 100
#define CTX_LEN 60
#define FACT_LEN 20
#define DESC_LEN 60
#define NCHUNK (VOCAB / 16)     // 6250 column chunks of 16
#define GRID_B 224
#define NWAVES_C (GRID_B * 4)   // 896 logit waves
#define CPW 7                   // ceil(6250/896) chunks per wave

// workspace layout (float offsets)
#define WS_FLAG  0              // 1 unsigned word; zeroed by kA (kernel-boundary ordered)
#define WS_H0    64             // 128
#define WS_GI    192            // 18000 (60 x 300)
#define WS_H     18192          // 6000  (60 x 100)
#define WS_MS    24256          // float2[60][896] = 107520 floats

typedef __attribute__((ext_vector_type(8))) short short8;
typedef __attribute__((ext_vector_type(4))) float f32x4;

static __device__ __forceinline__ unsigned short f2bf(float f) {
    union { float f; unsigned u; } x; x.f = f;
    unsigned r = (x.u + 0x7FFFu + ((x.u >> 16) & 1u)) >> 16;
    return (unsigned short)r;
}

// single-word producer->consumer handshake (silicon-validated pattern, rounds 3-4)
static __device__ __forceinline__ void release_flag(float* ws) {
    __builtin_amdgcn_fence(__ATOMIC_RELEASE, "agent");
    __hip_atomic_store((unsigned*)ws + WS_FLAG, 1u, __ATOMIC_RELAXED, __HIP_MEMORY_SCOPE_AGENT);
}
static __device__ __forceinline__ void wait_flag(const float* ws) {
    while (__hip_atomic_load((const unsigned*)ws + WS_FLAG, __ATOMIC_RELAXED,
                             __HIP_MEMORY_SCOPE_AGENT) == 0u)
        __builtin_amdgcn_s_sleep(16);
    __builtin_amdgcn_fence(__ATOMIC_ACQUIRE, "agent");
}

// ---------------- kA: h0 (blocks 0..99, facts recomputed in LDS) + gi (blocks 100..159) + init ----------------
__global__ __launch_bounds__(320) void kA(const int* __restrict__ context,
                                          const int* __restrict__ desc,
                                          const float* __restrict__ emb_ctx,
                                          const float* __restrict__ emb_dec,
                                          const float* __restrict__ w1,
                                          const float* __restrict__ b1,
                                          const float* __restrict__ w_ih,
                                          const float* __restrict__ b_ih,
                                          float* __restrict__ ws,
                                          float* __restrict__ out) {
    const int b = blockIdx.x, tid = threadIdx.x;
    if (b < 100) {
        __shared__ int toks[1200];
        __shared__ float facts[6000];
        __shared__ float red[320];
        for (int i = tid; i < 1200; i += 320) toks[i] = context[i];
        __syncthreads();
        // facts: bit-identical math to round-1 k1 (same fma order per element)
        for (int idx = tid; idx < 6000; idx += 320) {
            int fb = idx / 100, e = idx - fb * 100;
            float ef = e * (1.f / 99.f);
            float acc = 0.f;
            #pragma unroll
            for (int s = 0; s < 20; s++) {
                float sf = s * (1.f / 19.f);
                float l = 1.f - sf - ef * (1.f - 2.f * sf);
                acc = fmaf(emb_ctx[toks[fb * 20 + s] * 100 + e], l, acc);
            }
            facts[idx] = acc;
        }
        __syncthreads();
        // h0 row b: bit-identical reduction to round-1 k2
        const float* wr = w1 + b * 6000;
        float p = 0.f;
        for (int k = tid; k < 6000; k += 320) p = fmaf(facts[k], wr[k], p);
        red[tid] = p; __syncthreads();
        if (tid < 64) red[tid] += red[256 + tid];
        __syncthreads();
        for (int st = 128; st > 0; st >>= 1) {
            if (tid < st) red[tid] += red[tid + st];
            __syncthreads();
        }
        if (tid == 0) ws[WS_H0 + b] = red[0] + b1[b];
    } else {
        const int t = b - 100;
        const int tok = (t == 0) ? 1 : desc[t - 1];
        __shared__ float xs[100];
        if (tid < 100) xs[tid] = emb_dec[tok * 100 + tid];
        __syncthreads();
        if (tid < 300) {
            float p = b_ih[tid];
            const float* wr = w_ih + tid * 100;
            #pragma unroll 4
            for (int k = 0; k < 100; k++) p = fmaf(wr[k], xs[k], p);
            ws[WS_GI + t * 300 + tid] = p;
        }
        if (b == 100 && tid == 318) ((unsigned*)ws)[WS_FLAG] = 0u;  // flag: poisoned -> 0
        if (b == 100 && tid == 319) out[0] = 0.f;                   // out: poisoned -> 0
    }
}

// ---------------- kB: block 0 = GRU; blocks 1..223 = convert-to-regs; then ALL: logits + partials ----------------
__global__ __launch_bounds__(256, 1) void kB(const float* __restrict__ w_hh,
                                             const float* __restrict__ b_hh,
                                             const float* __restrict__ w_out,
                                             const float* __restrict__ b_out,
                                             float* __restrict__ ws) {
    __shared__ __align__(16) float smem[24128];   // gi 18000 + H 6000 + h_bf (GRU only)
    const int b = blockIdx.x, tid = threadIdx.x;
    const int lane = tid & 63, wave = tid >> 6;
    const int q = lane >> 4, n = lane & 15;
    const int gw = b * 4 + wave;                  // global wave id 0..895

    short8 bw[CPW][4];                            // per-wave w_out fragments (statically indexed)

    if (b != 0) {
        // ---- converters: fp32 w_out -> bf16 MFMA fragments in REGISTERS (round-3 scheme) ----
        #pragma unroll
        for (int k = 0; k < CPW; k++) {
            int c = gw + k * NWAVES_C;
            if (c < NCHUNK) {
                const float* wr = w_out + (c * 16 + n) * 100;
                #pragma unroll
                for (int kt = 0; kt < 4; kt++) {
                    int k0 = kt * 32 + q * 8;
                    float va[8];
                    #pragma unroll
                    for (int jj = 0; jj < 8; jj++) va[jj] = 0.f;
                    if (k0 + 4 <= 100) {
                        float4 a = *(const float4*)(wr + k0);
                        va[0] = a.x; va[1] = a.y; va[2] = a.z; va[3] = a.w;
                    }
                    if (k0 + 8 <= 100) {
                        float4 a = *(const float4*)(wr + k0 + 4);
                        va[4] = a.x; va[5] = a.y; va[6] = a.z; va[7] = a.w;
                    }
                    short8 f;
                    #pragma unroll
                    for (int jj = 0; jj < 8; jj++) f[jj] = (short)f2bf(va[jj]);
                    bw[k][kt] = f;
                }
            }
        }
        // wait for GRU's H (single poller per block; others park at the barrier)
        if (tid == 0) wait_flag(ws);
        __syncthreads();
    } else {
        // ---- block 0: sequential GRU (bit-identical to round-4 kB) ----
        float* gi_lds = smem;                                   // 18000
        float* H_lds  = smem + 18000;                           // 6000
        unsigned short (*h_bf)[128] = (unsigned short (*)[128])(smem + 24000);
        const int L = lane & 31;
        const int j = wave * 32 + L;
        const bool gate_lane = (lane < 32) && (j < 100);

        short8 bfr[3][2][4];
        #pragma unroll
        for (int s = 0; s < 3; s++) {
            #pragma unroll
            for (int c = 0; c < 2; c++) {
                const int jrow = wave * 32 + c * 16 + n;
                const float* wr = w_hh + (s * 100 + jrow) * 100;
                #pragma unroll
                for (int kt = 0; kt < 4; kt++) {
                    int k0 = kt * 32 + q * 8;
                    float va[8];
                    #pragma unroll
                    for (int jj = 0; jj < 8; jj++) va[jj] = 0.f;
                    if (jrow < 100) {
                        if (k0 + 4 <= 100) {
                            float4 a = *(const float4*)(wr + k0);
                            va[0] = a.x; va[1] = a.y; va[2] = a.z; va[3] = a.w;
                        }
                        if (k0 + 8 <= 100) {
                            float4 a = *(const float4*)(wr + k0 + 4);
                            va[4] = a.x; va[5] = a.y; va[6] = a.z; va[7] = a.w;
                        }
                    }
                    short8 f;
                    #pragma unroll
                    for (int jj = 0; jj < 8; jj++) f[jj] = (short)f2bf(va[jj]);
                    bfr[s][c][kt] = f;
                }
            }
        }

        {
            const float4* src = (const float4*)(ws + WS_GI);
            float4* dst = (float4*)gi_lds;
            for (int k = tid; k < 4500; k += 256) dst[k] = src[k];
        }

        float hreg = 0.f, bh0 = 0.f, bh1 = 0.f, bh2 = 0.f;
        if (gate_lane) {
            hreg = ws[WS_H0 + j];
            bh0 = b_hh[j]; bh1 = b_hh[100 + j]; bh2 = b_hh[200 + j];
        }
        if (tid < 128) {
            h_bf[0][tid] = (tid < 100) ? f2bf(ws[WS_H0 + tid]) : (unsigned short)0;
            h_bf[1][tid] = 0;
        }
        __syncthreads();

        const int js = (j < 100) ? j : 0;
        for (int t = 0; t < 60; t++) {
            const int rb = t & 1;
            float gir = gi_lds[t * 300 + js];
            float giz = gi_lds[t * 300 + 100 + js];
            float gin = gi_lds[t * 300 + 200 + js];

            short8 afr[4];
            #pragma unroll
            for (int kt = 0; kt < 4; kt++)
                afr[kt] = *(const short8*)&h_bf[rb][kt * 32 + q * 8];

            f32x4 acc[3][2];
            #pragma unroll
            for (int s = 0; s < 3; s++) {
                #pragma unroll
                for (int c = 0; c < 2; c++) {
                    f32x4 a = {0.f, 0.f, 0.f, 0.f};
                    a = __builtin_amdgcn_mfma_f32_16x16x32_bf16(afr[0], bfr[s][c][0], a, 0, 0, 0);
                    a = __builtin_amdgcn_mfma_f32_16x16x32_bf16(afr[1], bfr[s][c][1], a, 0, 0, 0);
                    a = __builtin_amdgcn_mfma_f32_16x16x32_bf16(afr[2], bfr[s][c][2], a, 0, 0, 0);
                    a = __builtin_amdgcn_mfma_f32_16x16x32_bf16(afr[3], bfr[s][c][3], a, 0, 0, 0);
                    acc[s][c] = a;
                }
            }

            if (gate_lane) {
                const int cc = L >> 4;
                float ghr = (cc ? acc[0][1][0] : acc[0][0][0]) + bh0;
                float ghz = (cc ? acc[1][1][0] : acc[1][0][0]) + bh1;
                float ghn = (cc ? acc[2][1][0] : acc[2][0][0]) + bh2;
                float r = 1.f / (1.f + __expf(-(gir + ghr)));
                float z = 1.f / (1.f + __expf(-(giz + ghz)));
                float a2 = fmaf(r, ghn, gin);
                float tt = __expf(-2.f * fabsf(a2));
                float nn = copysignf((1.f - tt) / (1.f + tt), a2);
                hreg = (1.f - z) * nn + z * hreg;
                h_bf[rb ^ 1][j] = f2bf(hreg);
                H_lds[t * 100 + j] = hreg;
            }
            __syncthreads();
        }

        {
            const float4* src = (const float4*)H_lds;
            float4* dst = (float4*)(ws + WS_H);
            for (int k = tid; k < 1500; k += 256) dst[k] = src[k];
        }
        __syncthreads();                          // drains all waves' H stores (vmcnt(0) before barrier)
        if (tid == 0) release_flag(ws);

        // block 0 converts its own chunks now (w_out hot in L3; ~trivial)
        #pragma unroll
        for (int k = 0; k < CPW; k++) {
            int c = gw + k * NWAVES_C;
            if (c < NCHUNK) {
                const float* wr = w_out + (c * 16 + n) * 100;
                #pragma unroll
                for (int kt = 0; kt < 4; kt++) {
                    int k0 = kt * 32 + q * 8;
                    float va[8];
                    #pragma unroll
                    for (int jj = 0; jj < 8; jj++) va[jj] = 0.f;
                    if (k0 + 4 <= 100) {
                        float4 a = *(const float4*)(wr + k0);
                        va[0] = a.x; va[1] = a.y; va[2] = a.z; va[3] = a.w;
                    }
                    if (k0 + 8 <= 100) {
                        float4 a = *(const float4*)(wr + k0 + 4);
                        va[4] = a.x; va[5] = a.y; va[6] = a.z; va[7] = a.w;
                    }
                    short8 f;
                    #pragma unroll
                    for (int jj = 0; jj < 8; jj++) f[jj] = (short)f2bf(va[jj]);
                    bw[k][kt] = f;
                }
            }
        }
    }

    // ================= logits GEMM + online softmax partials (all blocks) =================
    {
        const float* H = ws + WS_H;
        float* ms = ws + WS_MS;
        const int k_base = q * 8;

        short8 afr[4][4];
        #pragma unroll
        for (int mt = 0; mt < 4; mt++) {
            int m = mt * 16 + n;
            #pragma unroll
            for (int kt = 0; kt < 4; kt++) {
                int k0 = kt * 32 + k_base;
                float va[8];
                #pragma unroll
                for (int jj = 0; jj < 8; jj++) va[jj] = 0.f;
                if (m < 60) {
                    if (k0 + 4 <= 100) {
                        float4 a = *(const float4*)(H + m * 100 + k0);
                        va[0] = a.x; va[1] = a.y; va[2] = a.z; va[3] = a.w;
                    }
                    if (k0 + 8 <= 100) {
                        float4 a = *(const float4*)(H + m * 100 + k0 + 4);
                        va[4] = a.x; va[5] = a.y; va[6] = a.z; va[7] = a.w;
                    }
                }
                short8 f;
                #pragma unroll
                for (int jj = 0; jj < 8; jj++) f[jj] = (short)f2bf(va[jj]);
                afr[mt][kt] = f;
            }
        }

        float mS[16], sS[16];
        #pragma unroll
        for (int i = 0; i < 16; i++) { mS[i] = -3.0e38f; sS[i] = 0.f; }

        #pragma unroll
        for (int k = 0; k < CPW; k++) {
            int c = gw + k * NWAVES_C;
            if (c < NCHUNK) {
                int row = c * 16 + n;
                float bo = b_out[row];
                #pragma unroll
                for (int mt = 0; mt < 4; mt++) {
                    f32x4 acc = {0.f, 0.f, 0.f, 0.f};
                    acc = __builtin_amdgcn_mfma_f32_16x16x32_bf16(afr[mt][0], bw[k][0], acc, 0, 0, 0);
                    acc = __builtin_amdgcn_mfma_f32_16x16x32_bf16(afr[mt][1], bw[k][1], acc, 0, 0, 0);
                    acc = __builtin_amdgcn_mfma_f32_16x16x32_bf16(afr[mt][2], bw[k][2], acc, 0, 0, 0);
                    acc = __builtin_amdgcn_mfma_f32_16x16x32_bf16(afr[mt][3], bw[k][3], acc, 0, 0, 0);
                    #pragma unroll
                    for (int reg = 0; reg < 4; reg++) {
                        float x = acc[reg] + bo;
                        int i = mt * 4 + reg;
                        float mo = mS[i];
                        float mn = fmaxf(mo, x);
                        sS[i] = sS[i] * __expf(mo - mn) + __expf(x - mn);
                        mS[i] = mn;
                    }
                }
            }
        }

        #pragma unroll
        for (int i = 0; i < 16; i++) {
            float m = mS[i], s = sS[i];
            #pragma unroll
            for (int off = 1; off < 16; off <<= 1) {
                float m2 = __shfl_xor(m, off);
                float s2 = __shfl_xor(s, off);
                float mn = fmaxf(m, m2);
                s = s * __expf(m - mn) + s2 * __expf(m2 - mn);
                m = mn;
            }
            mS[i] = m; sS[i] = s;
        }
        if (n == 0) {
            #pragma unroll
            for (int mt = 0; mt < 4; mt++) {
                #pragma unroll
                for (int reg = 0; reg < 4; reg++) {
                    int t = mt * 16 + q * 4 + reg;
                    int i = mt * 4 + reg;
                    if (t < 60) {
                        float2 val; val.x = mS[i]; val.y = sS[i];
                        ((float2*)ms)[t * NWAVES_C + gw] = val;
                    }
                }
            }
        }
    }
}

// ---------------- kD: per-t combine + loss -> atomicAdd(out) ----------------
__global__ __launch_bounds__(256) void kD(const int* __restrict__ desc,
                                          const float* __restrict__ w_out,
                                          const float* __restrict__ b_out,
                                          const float* __restrict__ ws,
                                          float* __restrict__ out) {
    const int t = blockIdx.x, tid = threadIdx.x;
    __shared__ float sm[256], ss[256], sd[256];
    const float2* msp = (const float2*)(ws + WS_MS);
    float m = -3.0e38f, s = 0.f;
    for (int i = tid; i < NWAVES_C; i += 256) {
        float2 p2 = msp[t * NWAVES_C + i];
        float mn = fmaxf(m, p2.x);
        s = s * __expf(m - mn) + p2.y * __expf(p2.x - mn);
        m = mn;
    }
    sm[tid] = m; ss[tid] = s; __syncthreads();
    for (int st = 128; st > 0; st >>= 1) {
        if (tid < st) {
            float mo = sm[tid], so = ss[tid];
            float m2 = sm[tid + st], s2 = ss[tid + st];
            float mn = fmaxf(mo, m2);
            sm[tid] = mn;
            ss[tid] = so * __expf(mo - mn) + s2 * __expf(m2 - mn);
        }
        __syncthreads();
    }
    const int tok = desc[t];
    float p = 0.f;
    if (tid < 100) p = ws[WS_H + t * 100 + tid] * w_out[tok * 100 + tid];
    sd[tid] = p; __syncthreads();
    for (int st = 128; st > 0; st >>= 1) {
        if (tid < st) sd[tid] += sd[tid + st];
        __syncthreads();
    }
    if (tid == 0) {
        float logit = sd[0] + b_out[tok];
        atomicAdd(out, sm[0] + logf(ss[0]) - logit);
    }
}

extern "C" void kernel_launch(void* const* d_in, const int* in_sizes, int n_in,
                              void* d_out, int out_size, void* d_ws, size_t ws_size,
                              hipStream_t stream) {
    const int*   context = (const int*)d_in[0];
    // d_in[1] = fact_lengths (unused by reference)
    const int*   desc    = (const int*)d_in[2];
    const float* emb_ctx = (const float*)d_in[3];
    const float* emb_dec = (const float*)d_in[4];
    const float* w1      = (const float*)d_in[5];
    const float* b1      = (const float*)d_in[6];
    const float* w_ih    = (const float*)d_in[7];
    const float* w_hh    = (const float*)d_in[8];
    const float* b_ih    = (const float*)d_in[9];
    const float* b_hh    = (const float*)d_in[10];
    const float* w_out   = (const float*)d_in[11];
    const float* b_out   = (const float*)d_in[12];
    float* out = (float*)d_out;
    float* ws  = (float*)d_ws;

    kA<<<160, 320, 0, stream>>>(context, desc, emb_ctx, emb_dec, w1, b1, w_ih, b_ih, ws, out);
    kB<<<GRID_B, 256, 0, stream>>>(w_hh, b_hh, w_out, b_out, ws);
    kD<<<60, 256, 0, stream>>>(desc, w_out, b_out, ws, out);
}

// Round 7
// 201.854 us; speedup vs baseline: 1.0216x; 1.0216x over previous
//
#include <hip/hip_runtime.h>
#include <hip/hip_bf16.h>
#include <math.h>

#define VOCAB 100000
#define EMB 100
#define HID 100
#define CTX_LEN 60
#define FACT_LEN 20
#define DESC_LEN 60
#define NCHUNK (VOCAB / 16)     // 6250 column chunks of 16
#define GRID_B 224
#define NWAVES_T 892            // tail waves: blocks 1..223 x 4 (block 0 = GRU only)
#define CPW 8                   // ceil(6250/892)

// workspace layout (float offsets)
// flags: 4 unsigned words at unsigned offsets 0,16,32,48 (separate 64B lines); zeroed by kA
#define WS_H0    64             // 128
#define WS_GI    192            // 18000 (60 x 300)
#define WS_H     18192          // 6000  (60 x 100)
#define WS_MS    24256          // float2[60][892] = 107040 floats

typedef __attribute__((ext_vector_type(8))) short short8;
typedef __attribute__((ext_vector_type(4))) float f32x4;

static __device__ __forceinline__ unsigned short f2bf(float f) {
    union { float f; unsigned u; } x; x.f = f;
    unsigned r = (x.u + 0x7FFFu + ((x.u >> 16) & 1u)) >> 16;
    return (unsigned short)r;
}

// single-word producer->consumer handshake (silicon-validated, rounds 3-6)
static __device__ __forceinline__ void release_flag(float* ws, int idx) {
    __builtin_amdgcn_fence(__ATOMIC_RELEASE, "agent");
    __hip_atomic_store((unsigned*)ws + idx, 1u, __ATOMIC_RELAXED, __HIP_MEMORY_SCOPE_AGENT);
}
static __device__ __forceinline__ void wait_flag(const float* ws, int idx) {
    while (__hip_atomic_load((const unsigned*)ws + idx, __ATOMIC_RELAXED,
                             __HIP_MEMORY_SCOPE_AGENT) == 0u)
        __builtin_amdgcn_s_sleep(16);
    __builtin_amdgcn_fence(__ATOMIC_ACQUIRE, "agent");
}

// ---------------- kA: h0 (blocks 0..99, facts recomputed in LDS) + gi (blocks 100..159) + init ----------------
__global__ __launch_bounds__(320) void kA(const int* __restrict__ context,
                                          const int* __restrict__ desc,
                                          const float* __restrict__ emb_ctx,
                                          const float* __restrict__ emb_dec,
                                          const float* __restrict__ w1,
                                          const float* __restrict__ b1,
                                          const float* __restrict__ w_ih,
                                          const float* __restrict__ b_ih,
                                          float* __restrict__ ws,
                                          float* __restrict__ out) {
    const int b = blockIdx.x, tid = threadIdx.x;
    if (b < 100) {
        __shared__ int toks[1200];
        __shared__ float facts[6000];
        __shared__ float red[320];
        for (int i = tid; i < 1200; i += 320) toks[i] = context[i];
        __syncthreads();
        // facts: bit-identical math to round-1 k1 (same fma order per element)
        for (int idx = tid; idx < 6000; idx += 320) {
            int fb = idx / 100, e = idx - fb * 100;
            float ef = e * (1.f / 99.f);
            float acc = 0.f;
            #pragma unroll
            for (int s = 0; s < 20; s++) {
                float sf = s * (1.f / 19.f);
                float l = 1.f - sf - ef * (1.f - 2.f * sf);
                acc = fmaf(emb_ctx[toks[fb * 20 + s] * 100 + e], l, acc);
            }
            facts[idx] = acc;
        }
        __syncthreads();
        // h0 row b: bit-identical reduction to round-1 k2
        const float* wr = w1 + b * 6000;
        float p = 0.f;
        for (int k = tid; k < 6000; k += 320) p = fmaf(facts[k], wr[k], p);
        red[tid] = p; __syncthreads();
        if (tid < 64) red[tid] += red[256 + tid];
        __syncthreads();
        for (int st = 128; st > 0; st >>= 1) {
            if (tid < st) red[tid] += red[tid + st];
            __syncthreads();
        }
        if (tid == 0) ws[WS_H0 + b] = red[0] + b1[b];
    } else {
        const int t = b - 100;
        const int tok = (t == 0) ? 1 : desc[t - 1];
        __shared__ float xs[100];
        if (tid < 100) xs[tid] = emb_dec[tok * 100 + tid];
        __syncthreads();
        if (tid < 300) {
            float p = b_ih[tid];
            const float* wr = w_ih + tid * 100;
            #pragma unroll 4
            for (int k = 0; k < 100; k++) p = fmaf(wr[k], xs[k], p);
            ws[WS_GI + t * 300 + tid] = p;
        }
        if (b == 100) {
            if (tid >= 304 && tid < 308) ((unsigned*)ws)[(tid - 304) * 16] = 0u;  // flags -> 0
            if (tid == 319) out[0] = 0.f;                                          // out -> 0
        }
    }
}

// ---------------- kB: block 0 = GRU (releases 4 H-row flags); blocks 1..223 = convert + phased logits ----------------
__global__ __launch_bounds__(256, 1) void kB(const float* __restrict__ w_hh,
                                             const float* __restrict__ b_hh,
                                             const float* __restrict__ w_out,
                                             const float* __restrict__ b_out,
                                             float* __restrict__ ws) {
    __shared__ __align__(16) float smem[18128];   // gi 18000 + h_bf 2x128 (GRU only)
    const int b = blockIdx.x, tid = threadIdx.x;
    const int lane = tid & 63, wave = tid >> 6;
    const int q = lane >> 4, n = lane & 15;

    if (b == 0) {
        // ---- sequential GRU (bit-identical consumed math to rounds 4/6) ----
        float* gi_lds = smem;                                   // 18000
        unsigned short (*h_bf)[128] = (unsigned short (*)[128])(smem + 18000);
        const int L = lane & 31;
        const int j = wave * 32 + L;
        const bool gate_lane = (lane < 32) && (j < 100);

        short8 bfr[3][2][4];
        #pragma unroll
        for (int s = 0; s < 3; s++) {
            #pragma unroll
            for (int c = 0; c < 2; c++) {
                const int jrow = wave * 32 + c * 16 + n;
                const float* wr = w_hh + (s * 100 + jrow) * 100;
                #pragma unroll
                for (int kt = 0; kt < 4; kt++) {
                    int k0 = kt * 32 + q * 8;
                    float va[8];
                    #pragma unroll
                    for (int jj = 0; jj < 8; jj++) va[jj] = 0.f;
                    if (jrow < 100) {
                        if (k0 + 4 <= 100) {
                            float4 a = *(const float4*)(wr + k0);
                            va[0] = a.x; va[1] = a.y; va[2] = a.z; va[3] = a.w;
                        }
                        if (k0 + 8 <= 100) {
                            float4 a = *(const float4*)(wr + k0 + 4);
                            va[4] = a.x; va[5] = a.y; va[6] = a.z; va[7] = a.w;
                        }
                    }
                    short8 f;
                    #pragma unroll
                    for (int jj = 0; jj < 8; jj++) f[jj] = (short)f2bf(va[jj]);
                    bfr[s][c][kt] = f;
                }
            }
        }

        {
            const float4* src = (const float4*)(ws + WS_GI);
            float4* dst = (float4*)gi_lds;
            for (int k = tid; k < 4500; k += 256) dst[k] = src[k];
        }

        float hreg = 0.f, bh0 = 0.f, bh1 = 0.f, bh2 = 0.f;
        if (gate_lane) {
            hreg = ws[WS_H0 + j];
            bh0 = b_hh[j]; bh1 = b_hh[100 + j]; bh2 = b_hh[200 + j];
        }
        if (tid < 128) {
            h_bf[0][tid] = (tid < 100) ? f2bf(ws[WS_H0 + tid]) : (unsigned short)0;
            h_bf[1][tid] = 0;
        }
        __syncthreads();

        const int js = (j < 100) ? j : 0;
        for (int t = 0; t < 60; t++) {
            const int rb = t & 1;
            float gir = gi_lds[t * 300 + js];
            float giz = gi_lds[t * 300 + 100 + js];
            float gin = gi_lds[t * 300 + 200 + js];

            short8 afr[4];
            #pragma unroll
            for (int kt = 0; kt < 4; kt++)
                afr[kt] = *(const short8*)&h_bf[rb][kt * 32 + q * 8];

            f32x4 acc[3][2];
            #pragma unroll
            for (int s = 0; s < 3; s++) {
                #pragma unroll
                for (int c = 0; c < 2; c++) {
                    f32x4 a = {0.f, 0.f, 0.f, 0.f};
                    a = __builtin_amdgcn_mfma_f32_16x16x32_bf16(afr[0], bfr[s][c][0], a, 0, 0, 0);
                    a = __builtin_amdgcn_mfma_f32_16x16x32_bf16(afr[1], bfr[s][c][1], a, 0, 0, 0);
                    a = __builtin_amdgcn_mfma_f32_16x16x32_bf16(afr[2], bfr[s][c][2], a, 0, 0, 0);
                    a = __builtin_amdgcn_mfma_f32_16x16x32_bf16(afr[3], bfr[s][c][3], a, 0, 0, 0);
                    acc[s][c] = a;
                }
            }

            if (gate_lane) {
                const int cc = L >> 4;
                float ghr = (cc ? acc[0][1][0] : acc[0][0][0]) + bh0;
                float ghz = (cc ? acc[1][1][0] : acc[1][0][0]) + bh1;
                float ghn = (cc ? acc[2][1][0] : acc[2][0][0]) + bh2;
                float r = 1.f / (1.f + __expf(-(gir + ghr)));
                float z = 1.f / (1.f + __expf(-(giz + ghz)));
                float a2 = fmaf(r, ghn, gin);
                float tt = __expf(-2.f * fabsf(a2));
                float nn = copysignf((1.f - tt) / (1.f + tt), a2);
                hreg = (1.f - z) * nn + z * hreg;
                h_bf[rb ^ 1][j] = f2bf(hreg);
                ws[WS_H + t * 100 + j] = hreg;    // direct global store (round-0 pattern)
            }
            __syncthreads();                      // drains each wave's vmcnt before barrier
            if (t == 15 || t == 31 || t == 47 || t == 59) {
                if (tid == 0) release_flag(ws, (t >> 4) * 16);   // H rows [0, 16*(p+1)) visible
            }
        }
        return;                                   // block 0 takes no tail work
    }

    // ---- blocks 1..223: convert own chunks to registers, then 4 H-row phases ----
    const int gw = (b - 1) * 4 + wave;            // tail wave id 0..891
    short8 bw[CPW][4];                            // statically indexed only
    #pragma unroll
    for (int k = 0; k < CPW; k++) {
        int c = gw + k * NWAVES_T;
        if (c < NCHUNK) {
            const float* wr = w_out + (c * 16 + n) * 100;
            #pragma unroll
            for (int kt = 0; kt < 4; kt++) {
                int k0 = kt * 32 + q * 8;
                float va[8];
                #pragma unroll
                for (int jj = 0; jj < 8; jj++) va[jj] = 0.f;
                if (k0 + 4 <= 100) {
                    float4 a = *(const float4*)(wr + k0);
                    va[0] = a.x; va[1] = a.y; va[2] = a.z; va[3] = a.w;
                }
                if (k0 + 8 <= 100) {
                    float4 a = *(const float4*)(wr + k0 + 4);
                    va[4] = a.x; va[5] = a.y; va[6] = a.z; va[7] = a.w;
                }
                short8 f;
                #pragma unroll
                for (int jj = 0; jj < 8; jj++) f[jj] = (short)f2bf(va[jj]);
                bw[k][kt] = f;
            }
        }
    }

    const float* H = ws + WS_H;
    const int k_base = q * 8;
    float mS[16], sS[16];
    #pragma unroll
    for (int i = 0; i < 16; i++) { mS[i] = -3.0e38f; sS[i] = 0.f; }

    #pragma unroll
    for (int p = 0; p < 4; p++) {                 // fully unrolled: all mS/sS indices static
        if (tid == 0) wait_flag(ws, p * 16);
        __syncthreads();

        // afr for H rows [16p, 16p+16): identical construction to round 6's afr[p][*]
        short8 afr[4];
        const int m = p * 16 + n;
        #pragma unroll
        for (int kt = 0; kt < 4; kt++) {
            int k0 = kt * 32 + k_base;
            float va[8];
            #pragma unroll
            for (int jj = 0; jj < 8; jj++) va[jj] = 0.f;
            if (m < 60) {
                if (k0 + 4 <= 100) {
                    float4 a = *(const float4*)(H + m * 100 + k0);
                    va[0] = a.x; va[1] = a.y; va[2] = a.z; va[3] = a.w;
                }
                if (k0 + 8 <= 100) {
                    float4 a = *(const float4*)(H + m * 100 + k0 + 4);
                    va[4] = a.x; va[5] = a.y; va[6] = a.z; va[7] = a.w;
                }
            }
            short8 f;
            #pragma unroll
            for (int jj = 0; jj < 8; jj++) f[jj] = (short)f2bf(va[jj]);
            afr[kt] = f;
        }

        #pragma unroll
        for (int k = 0; k < CPW; k++) {
            int c = gw + k * NWAVES_T;
            if (c < NCHUNK) {
                int row = c * 16 + n;
                float bo = b_out[row];
                f32x4 acc = {0.f, 0.f, 0.f, 0.f};
                acc = __builtin_amdgcn_mfma_f32_16x16x32_bf16(afr[0], bw[k][0], acc, 0, 0, 0);
                acc = __builtin_amdgcn_mfma_f32_16x16x32_bf16(afr[1], bw[k][1], acc, 0, 0, 0);
                acc = __builtin_amdgcn_mfma_f32_16x16x32_bf16(afr[2], bw[k][2], acc, 0, 0, 0);
                acc = __builtin_amdgcn_mfma_f32_16x16x32_bf16(afr[3], bw[k][3], acc, 0, 0, 0);
                #pragma unroll
                for (int reg = 0; reg < 4; reg++) {
                    float x = acc[reg] + bo;      // logit for (t = p*16+q*4+reg, v = row)
                    const int i = p * 4 + reg;    // static: p,reg both unrolled
                    float mo = mS[i];
                    float mn = fmaxf(mo, x);
                    sS[i] = sS[i] * __expf(mo - mn) + __expf(x - mn);
                    mS[i] = mn;
                }
            }
        }
    }

    // reduce (m,s) across the 16 column lanes — identical to round 6
    #pragma unroll
    for (int i = 0; i < 16; i++) {
        float m = mS[i], s = sS[i];
        #pragma unroll
        for (int off = 1; off < 16; off <<= 1) {
            float m2 = __shfl_xor(m, off);
            float s2 = __shfl_xor(s, off);
            float mn = fmaxf(m, m2);
            s = s * __expf(m - mn) + s2 * __expf(m2 - mn);
            m = mn;
        }
        mS[i] = m; sS[i] = s;
    }
    if (n == 0) {
        float* ms = ws + WS_MS;
        #pragma unroll
        for (int mt = 0; mt < 4; mt++) {
            #pragma unroll
            for (int reg = 0; reg < 4; reg++) {
                int t = mt * 16 + q * 4 + reg;
                int i = mt * 4 + reg;
                if (t < 60) {
                    float2 val; val.x = mS[i]; val.y = sS[i];
                    ((float2*)ms)[t * NWAVES_T + gw] = val;
                }
            }
        }
    }
}

// ---------------- kD: per-t combine + loss -> atomicAdd(out) ----------------
__global__ __launch_bounds__(256) void kD(const int* __restrict__ desc,
                                          const float* __restrict__ w_out,
                                          const float* __restrict__ b_out,
                                          const float* __restrict__ ws,
                                          float* __restrict__ out) {
    const int t = blockIdx.x, tid = threadIdx.x;
    __shared__ float sm[256], ss[256], sd[256];
    const float2* msp = (const float2*)(ws + WS_MS);
    float m = -3.0e38f, s = 0.f;
    for (int i = tid; i < NWAVES_T; i += 256) {
        float2 p2 = msp[t * NWAVES_T + i];
        float mn = fmaxf(m, p2.x);
        s = s * __expf(m - mn) + p2.y * __expf(p2.x - mn);
        m = mn;
    }
    sm[tid] = m; ss[tid] = s; __syncthreads();
    for (int st = 128; st > 0; st >>= 1) {
        if (tid < st) {
            float mo = sm[tid], so = ss[tid];
            float m2 = sm[tid + st], s2 = ss[tid + st];
            float mn = fmaxf(mo, m2);
            sm[tid] = mn;
            ss[tid] = so * __expf(mo - mn) + s2 * __expf(m2 - mn);
        }
        __syncthreads();
    }
    const int tok = desc[t];
    float p = 0.f;
    if (tid < 100) p = ws[WS_H + t * 100 + tid] * w_out[tok * 100 + tid];
    sd[tid] = p; __syncthreads();
    for (int st = 128; st > 0; st >>= 1) {
        if (tid < st) sd[tid] += sd[tid + st];
        __syncthreads();
    }
    if (tid == 0) {
        float logit = sd[0] + b_out[tok];
        atomicAdd(out, sm[0] + logf(ss[0]) - logit);
    }
}

extern "C" void kernel_launch(void* const* d_in, const int* in_sizes, int n_in,
                              void* d_out, int out_size, void* d_ws, size_t ws_size,
                              hipStream_t stream) {
    const int*   context = (const int*)d_in[0];
    // d_in[1] = fact_lengths (unused by reference)
    const int*   desc    = (const int*)d_in[2];
    const float* emb_ctx = (const float*)d_in[3];
    const float* emb_dec = (const float*)d_in[4];
    const float* w1      = (const float*)d_in[5];
    const float* b1      = (const float*)d_in[6];
    const float* w_ih    = (const float*)d_in[7];
    const float* w_hh    = (const float*)d_in[8];
    const float* b_ih    = (const float*)d_in[9];
    const float* b_hh    = (const float*)d_in[10];
    const float* w_out   = (const float*)d_in[11];
    const float* b_out   = (const float*)d_in[12];
    float* out = (float*)d_out;
    float* ws  = (float*)d_ws;

    kA<<<160, 320, 0, stream>>>(context, desc, emb_ctx, emb_dec, w1, b1, w_ih, b_ih, ws, out);
    kB<<<GRID_B, 256, 0, stream>>>(w_hh, b_hh, w_out, b_out, ws);
    kD<<<60, 256, 0, stream>>>(desc, w_out, b_out, ws, out);
}